// Round 3
// baseline (67.297 us; speedup 1.0000x reference)
//
#include <hip/hip_runtime.h>

#define LEAKY(x) ((x) > 0.0f ? (x) : 0.01f * (x))

// ws float layout
#define UE_OFF 0                 // 16384 floats (reused as g-output after circuit)
#define AP_OFF 16384             // 4096
#define EA_OFF 20480             // 49152
#define ME_OFF 69632             // 32   : M_edge 4x4 complex
#define U0C_OFF 69664            // 128  : U0 cols {0,4,8,12}, [j][r] col-major
#define U1T_OFF 69792            // 512  : U1 [q][r] (col-major)
#define GP_OFF 70304             // 1536 : 3 x permuted G_w [(c*2+n)*16 + (c'*2+n')]

__device__ __forceinline__ float2 cmul(float2 a, float2 b) {
  return make_float2(fmaf(a.x, b.x, -a.y * b.y), fmaf(a.x, b.y, a.y * b.x));
}
__device__ __forceinline__ float2 cmulc(float2 a, float2 b) {  // conj(a)*b
  return make_float2(fmaf(a.x, b.x, a.y * b.y), fmaf(a.x, b.y, -a.y * b.x));
}
__device__ __forceinline__ float2 cadd(float2 a, float2 b) {
  return make_float2(a.x + b.x, a.y + b.y);
}
__device__ __forceinline__ float2 csub(float2 a, float2 b) {
  return make_float2(a.x - b.x, a.y - b.y);
}
__device__ __forceinline__ void swap2(float2& a, float2& b) {
  float2 t = a; a = b; b = t;
}

struct C2 { float2 e[4]; }; // row-major 2x2 complex

__device__ C2 cmm(const C2& A, const C2& B) {
  C2 R;
  #pragma unroll
  for (int r = 0; r < 2; ++r)
    #pragma unroll
    for (int c = 0; c < 2; ++c)
      R.e[r*2+c] = cadd(cmul(A.e[r*2+0], B.e[0*2+c]), cmul(A.e[r*2+1], B.e[1*2+c]));
  return R;
}
__device__ C2 gRX(float t) {
  float s, c; sincosf(0.5f*t, &s, &c);
  C2 M;
  M.e[0] = make_float2(c, 0.f);  M.e[1] = make_float2(0.f, -s);
  M.e[2] = make_float2(0.f, -s); M.e[3] = make_float2(c, 0.f);
  return M;
}
__device__ C2 gRY(float t) {
  float s, c; sincosf(0.5f*t, &s, &c);
  C2 M;
  M.e[0] = make_float2(c, 0.f);  M.e[1] = make_float2(-s, 0.f);
  M.e[2] = make_float2(s, 0.f);  M.e[3] = make_float2(c, 0.f);
  return M;
}
__device__ C2 gRZ(float t) {
  float s, c; sincosf(0.5f*t, &s, &c);
  C2 M;
  M.e[0] = make_float2(c, -s);    M.e[1] = make_float2(0.f, 0.f);
  M.e[2] = make_float2(0.f, 0.f); M.e[3] = make_float2(c, s);
  return M;
}
__device__ C2 gROT(float phi, float th, float om) {
  return cmm(cmm(gRZ(om), gRY(th)), gRZ(phi));
}

// 2-layer MLP encoder, 8 threads per row, 32 rows per 256-thread block.
template<int D>
__device__ void enc_rows(const float* __restrict__ x, int rbase,
                         const float* __restrict__ W1, const float* __restrict__ b1,
                         const float* __restrict__ W2, const float* __restrict__ b2,
                         float* __restrict__ out) {
  const int tid = threadIdx.x;
  const int r = rbase + (tid >> 3), sub = tid & 7;
  float xi[D];
  #pragma unroll
  for (int k = 0; k < D; ++k) xi[k] = x[r*D + k];
  float o0 = 0.f, o1 = 0.f;
  #pragma unroll
  for (int jj = 0; jj < 16; ++jj) {
    int j = jj*8 + sub;
    float h = b1[j];
    #pragma unroll
    for (int k = 0; k < D; ++k) h = fmaf(xi[k], W1[k*128 + j], h);
    h = LEAKY(h);
    o0 = fmaf(h, W2[j*2 + 0], o0);
    o1 = fmaf(h, W2[j*2 + 1], o1);
  }
  #pragma unroll
  for (int o = 4; o; o >>= 1) { o0 += __shfl_xor(o0, o); o1 += __shfl_xor(o1, o); }
  if (sub == 0) {
    out[r*2 + 0] = o0 + b2[0];
    out[r*2 + 1] = o1 + b2[1];
  }
}

// Fused: 3 encoders + gate-algebra precompute (block 1088).
__global__ __launch_bounds__(256) void prep_kernel(
    const float* __restrict__ x_ue, const float* __restrict__ x_ap,
    const float* __restrict__ edge_attr,
    const float* __restrict__ Wn1u, const float* __restrict__ bn1u,
    const float* __restrict__ Wn2u, const float* __restrict__ bn2u,
    const float* __restrict__ Wn1a, const float* __restrict__ bn1a,
    const float* __restrict__ Wn2a, const float* __restrict__ bn2a,
    const float* __restrict__ We1,  const float* __restrict__ be1,
    const float* __restrict__ We2,  const float* __restrict__ be2,
    const float* __restrict__ strongp, const float* __restrict__ initsp,
    const float* __restrict__ updatep, float* __restrict__ ws) {
  const int bi = blockIdx.x;
  if (bi < 256) {
    enc_rows<8>(x_ue, bi*32, Wn1u, bn1u, Wn2u, bn2u, ws + UE_OFF);
  } else if (bi < 320) {
    enc_rows<8>(x_ap, (bi-256)*32, Wn1a, bn1a, Wn2a, bn2a, ws + AP_OFF);
  } else if (bi < 1088) {
    enc_rows<4>(edge_attr, (bi-320)*32, We1, be1, We2, be2, ws + EA_OFF);
  } else {
    // ---- gate algebra block ----
    __shared__ float2 U2s[16][17];
    const int tid = threadIdx.x;
    if (tid < 48) {
      // build U_k (k = tid>>4) column col = tid&15.
      // q-space bit masks: wire3=8, nb=4, wire7=2, wire8=1.
      const int k = tid >> 4, col = tid & 15;
      float2 u[16];
      #pragma unroll
      for (int r = 0; r < 16; ++r) u[r] = make_float2(r == col ? 1.f : 0.f, 0.f);
      #pragma unroll
      for (int l = 0; l < 2; ++l) {
        #pragma unroll
        for (int j = 0; j < 4; ++j) {
          const float* p = updatep + k*24 + l*12 + j*3;
          C2 U = gROT(p[0], p[1], p[2]);
          const int m = 8 >> j;
          #pragma unroll
          for (int r = 0; r < 16; ++r)
            if (!(r & m)) {
              float2 t0 = u[r], t1 = u[r | m];
              u[r]     = cadd(cmul(U.e[0], t0), cmul(U.e[1], t1));
              u[r | m] = cadd(cmul(U.e[2], t0), cmul(U.e[3], t1));
            }
        }
        // CX list: l=0: (8->4),(4->2),(2->1),(1->8); l=1: (8->2),(4->1),(2->8),(1->4)
        #pragma unroll
        for (int j = 0; j < 4; ++j) {
          const int mc = 8 >> j;
          const int mt0[4] = {4, 2, 1, 8};
          const int mt1[4] = {2, 1, 8, 4};
          const int mt = (l == 0) ? mt0[j] : mt1[j];
          #pragma unroll
          for (int r = 0; r < 16; ++r)
            if ((r & mc) && !(r & mt)) swap2(u[r], u[r | mt]);
        }
      }
      if (k == 0) {
        if (!(col & 3)) {
          const int jc = col >> 2;
          #pragma unroll
          for (int r = 0; r < 16; ++r) {
            ws[U0C_OFF + (jc*16 + r)*2 + 0] = u[r].x;
            ws[U0C_OFF + (jc*16 + r)*2 + 1] = u[r].y;
          }
        }
      } else if (k == 1) {
        #pragma unroll
        for (int r = 0; r < 16; ++r) {
          ws[U1T_OFF + (col*16 + r)*2 + 0] = u[r].x;
          ws[U1T_OFF + (col*16 + r)*2 + 1] = u[r].y;
        }
      } else {
        #pragma unroll
        for (int r = 0; r < 16; ++r) U2s[col][r] = u[r];   // U2s[q][t] = U2[t][q]
      }
    }
    if (tid == 48) {
      // ---- M_edge 4x4 (basis (b_e<<1)|b_nb) — verified construction
      float2 M[4][4];
      #pragma unroll
      for (int r = 0; r < 4; ++r)
        #pragma unroll
        for (int c = 0; c < 4; ++c)
          M[r][c] = make_float2(r == c ? 1.f : 0.f, 0.f);
      auto rowpair = [&](int r0, int r1, C2 U) {
        #pragma unroll
        for (int c = 0; c < 4; ++c) {
          float2 a0 = M[r0][c], a1 = M[r1][c];
          M[r0][c] = cadd(cmul(U.e[0], a0), cmul(U.e[1], a1));
          M[r1][c] = cadd(cmul(U.e[2], a0), cmul(U.e[3], a1));
        }
      };
      auto rowswap = [&](int r0, int r1) {
        #pragma unroll
        for (int c = 0; c < 4; ++c) swap2(M[r0][c], M[r1][c]);
      };
      rowpair(1, 3, gRX(initsp[0]));
      rowpair(2, 3, gRY(initsp[1]));
      #pragma unroll
      for (int l = 0; l < 2; ++l) {
        C2 Re = gROT(strongp[l*6+0], strongp[l*6+1], strongp[l*6+2]);
        C2 Rn = gROT(strongp[l*6+3], strongp[l*6+4], strongp[l*6+5]);
        rowpair(0, 2, Re); rowpair(1, 3, Re);
        rowpair(0, 1, Rn); rowpair(2, 3, Rn);
        rowswap(2, 3);
        rowswap(1, 3);
      }
      #pragma unroll
      for (int r = 0; r < 4; ++r)
        #pragma unroll
        for (int c = 0; c < 4; ++c) {
          ws[ME_OFF + (r*4 + c)*2 + 0] = M[r][c].x;
          ws[ME_OFF + (r*4 + c)*2 + 1] = M[r][c].y;
        }
    }
    __syncthreads();
    if (tid < 64) {
      // G_w[q,q'] = sum_t conj(U2[t,q]) s_w(t) U2[t,q'], stored permuted:
      // GP[w][(c*2+n)*16 + (c'*2+n')] with q=m(c,n)=((c&4)<<1)|(n<<2)|(c&3)
      const int c = tid >> 3, cp = tid & 7;
      #pragma unroll
      for (int n = 0; n < 2; ++n)
        #pragma unroll
        for (int np = 0; np < 2; ++np) {
          const int q  = ((c  & 4) << 1) | (n  << 2) | (c  & 3);
          const int qp = ((cp & 4) << 1) | (np << 2) | (cp & 3);
          float2 g3 = make_float2(0,0), g7 = g3, g8 = g3;
          #pragma unroll
          for (int t = 0; t < 16; ++t) {
            float2 pr = cmulc(U2s[q][t], U2s[qp][t]);
            g3 = (t & 8) ? csub(g3, pr) : cadd(g3, pr);
            g7 = (t & 2) ? csub(g7, pr) : cadd(g7, pr);
            g8 = (t & 1) ? csub(g8, pr) : cadd(g8, pr);
          }
          const int idx = (c*2 + n)*16 + (cp*2 + np);
          ws[GP_OFF + (0*256 + idx)*2 + 0] = g3.x;
          ws[GP_OFF + (0*256 + idx)*2 + 1] = g3.y;
          ws[GP_OFF + (1*256 + idx)*2 + 0] = g7.x;
          ws[GP_OFF + (1*256 + idx)*2 + 1] = g7.y;
          ws[GP_OFF + (2*256 + idx)*2 + 0] = g8.x;
          ws[GP_OFF + (2*256 + idx)*2 + 1] = g8.y;
        }
    }
  }
}

// One wave per UE; branch-traced simulation. Writes g (2 floats/UE) into UE region.
__global__ __launch_bounds__(128) void circuit_kernel(
    float* __restrict__ ws, const int* __restrict__ esrc,
    const float* __restrict__ Wu1, const float* __restrict__ bu1,
    const float* __restrict__ Wu2, const float* __restrict__ bu2,
    const float* __restrict__ lng, const float* __restrict__ lnb) {
  __shared__ float2 consts[336];            // ME(16) | U0c(64: [j][r]) | U1t(256: [q][r])
  __shared__ float2 pr_s[2][3][4];
  __shared__ float2 psi0[2][2][16];
  __shared__ float2 psi2[2][8][16];
  const int tid = threadIdx.x, wv = tid >> 6, lane = tid & 63;
  const int u = blockIdx.x*2 + wv;

  // --- A: stage constants (ME..U1T are contiguous 336 float2 in ws)
  {
    const float2* src = (const float2*)(ws + ME_OFF);
    for (int i = tid; i < 336; i += 128) consts[i] = src[i];
  }
  const float2* MEs = consts;
  const float2* U0c = consts + 16;    // [j][r] : j*16+r
  const float2* U1t = consts + 80;    // [q][r] : q*16+r

  // --- B: init single-qubit states + pair vectors
  const float* uep = ws + UE_OFF;
  const float* app = ws + AP_OFF;
  const float* eap = ws + EA_OFF;
  const float ue0 = uep[u*2 + 0], ue1 = uep[u*2 + 1];
  auto mkv = [](float aa, float bb, float2& v0, float2& v1) {
    float sa, ca, sb, cb;
    sincosf(0.5f*aa, &sa, &ca);
    sincosf(0.5f*bb, &sb, &cb);
    v0 = make_float2(cb*ca, -sb*ca);
    v1 = make_float2(sa*sb, -sa*cb);
  };
  float2 t0, t1;
  mkv(ue0, ue1, t0, t1);
  if (lane < 12) {
    const int i = lane >> 2, r = lane & 3;
    float2 ev0, ev1, nv0, nv1;
    mkv(eap[(u*3 + i)*2 + 0], eap[(u*3 + i)*2 + 1], ev0, ev1);
    const int s = esrc[u*3 + i];
    mkv(app[s*2 + 0], app[s*2 + 1], nv0, nv1);
    float2 in4[4] = {cmul(ev0, nv0), cmul(ev0, nv1), cmul(ev1, nv0), cmul(ev1, nv1)};
    float2 acc = make_float2(0.f, 0.f);
    #pragma unroll
    for (int c = 0; c < 4; ++c) acc = cadd(acc, cmul(MEs[r*4 + c], in4[c]));
    pr_s[wv][i][r] = acc;
  }
  __syncthreads();

  // --- C: block0 — 2 branches x 16 rows (lanes 0..31)
  if (lane < 32) {
    const int b = lane >> 4, row = lane & 15;
    float2 acc = make_float2(0.f, 0.f);
    #pragma unroll
    for (int j = 0; j < 4; ++j) {            // j = (c3<<1)|n -> col q'=4j
      float2 phi = pr_s[wv][0][(b << 1) | (j & 1)];
      float2 coef = cmul((j >> 1) ? t1 : t0, phi);
      acc = cadd(acc, cmul(U0c[j*16 + row], coef));
    }
    psi0[wv][b][row] = acc;
  }
  __syncthreads();

  // --- D: block1 — 8 input-branches x 16 rows, 2 rows/lane
  {
    const int ibr = lane >> 3, rp = lane & 7;
    const int db = ibr >> 2, da = (ibr >> 1) & 1, dbp = ibr & 1;
    const float2 f10 = pr_s[wv][1][(dbp << 1) | 0];
    const float2 f11 = pr_s[wv][1][(dbp << 1) | 1];
    float2 chi[8];
    #pragma unroll
    for (int cc = 0; cc < 8; ++cc)
      chi[cc] = psi0[wv][db][((cc & 4) << 1) | (da << 2) | (cc & 3)];
    float2 o0 = make_float2(0.f, 0.f), o1 = o0;
    #pragma unroll
    for (int q = 0; q < 16; ++q) {
      const int cc = ((q >> 3) << 2) | (q & 3);
      float2 xq = cmul(chi[cc], (q & 4) ? f11 : f10);
      o0 = cadd(o0, cmul(U1t[q*16 + rp],     xq));
      o1 = cadd(o1, cmul(U1t[q*16 + rp + 8], xq));
    }
    psi2[wv][ibr][rp]     = o0;
    psi2[wv][ibr][rp + 8] = o1;
  }
  __syncthreads();

  // --- E: branch Gram matrix R[c,c'] (one entry per lane)
  const int c = lane >> 3, cp = lane & 7;
  float2 R = make_float2(0.f, 0.f);
  #pragma unroll
  for (int br = 0; br < 8; ++br)
    #pragma unroll
    for (int a2 = 0; a2 < 2; ++a2) {
      float2 z1 = psi2[wv][br][((c  & 4) << 1) | (a2 << 2) | (c  & 3)];
      float2 z2 = psi2[wv][br][((cp & 4) << 1) | (a2 << 2) | (cp & 3)];
      R.x += z1.x*z2.x + z1.y*z2.y;          // z1 * conj(z2)
      R.y += z1.y*z2.x - z1.x*z2.y;
    }

  // --- F: rho2, K_w, E_w
  const float2 f20 = pr_s[wv][2][0], f21 = pr_s[wv][2][1];
  const float2 f22 = pr_s[wv][2][2], f23 = pr_s[wv][2][3];
  float2 rho[2][2];
  rho[0][0] = cadd(cmulc(f20, f20), cmulc(f22, f22));  // note cmulc(a,a) = |a|^2 real
  rho[0][1] = make_float2(fmaf(f20.x,f21.x,f20.y*f21.y) + fmaf(f22.x,f23.x,f22.y*f23.y),
                          (f20.y*f21.x - f20.x*f21.y) + (f22.y*f23.x - f22.x*f23.y));
  rho[1][0] = make_float2(rho[0][1].x, -rho[0][1].y);
  rho[1][1] = cadd(cmulc(f21, f21), cmulc(f23, f23));
  // fix rho[0][0]/[1][1] to be phi[b][n'] * conj(phi[b][n]) with n'=n (real):
  rho[0][0] = make_float2(f20.x*f20.x + f20.y*f20.y + f22.x*f22.x + f22.y*f22.y, 0.f);
  rho[1][1] = make_float2(f21.x*f21.x + f21.y*f21.y + f23.x*f23.x + f23.y*f23.y, 0.f);
  // rho[0][1] = sum_b phi[b][0]*conj(phi[b][1]):
  rho[0][1] = make_float2(fmaf(f20.x,f21.x,f20.y*f21.y) + fmaf(f22.x,f23.x,f22.y*f23.y),
                          (f20.y*f21.x - f20.x*f21.y) + (f22.y*f23.x - f22.x*f23.y));
  rho[1][0] = make_float2(rho[0][1].x, -rho[0][1].y);

  float ev[3];
  {
    const float2* gp = (const float2*)(ws + GP_OFF);
    #pragma unroll
    for (int w = 0; w < 3; ++w) {
      float2 K = make_float2(0.f, 0.f);
      #pragma unroll
      for (int n = 0; n < 2; ++n)
        #pragma unroll
        for (int np = 0; np < 2; ++np) {
          float2 g = gp[w*256 + (c*2 + n)*16 + (cp*2 + np)];
          K = cadd(K, cmul(g, rho[np][n]));
        }
      ev[w] = K.x*R.x + K.y*R.y;             // Re(K * conj(R))
    }
  }
  #pragma unroll
  for (int o = 32; o; o >>= 1) {
    ev[0] += __shfl_xor(ev[0], o);
    ev[1] += __shfl_xor(ev[1], o);
    ev[2] += __shfl_xor(ev[2], o);
  }

  // --- G: Wu MLP + residual + LN -> g
  const int j1 = lane, j2 = lane + 64;
  float in5[5] = {ue0, ue1, ev[0], ev[1], ev[2]};
  float h1 = bu1[j1], h2 = bu1[j2];
  #pragma unroll
  for (int k = 0; k < 5; ++k) {
    h1 = fmaf(in5[k], Wu1[k*128 + j1], h1);
    h2 = fmaf(in5[k], Wu1[k*128 + j2], h2);
  }
  h1 = LEAKY(h1); h2 = LEAKY(h2);
  float p0 = h1*Wu2[j1*2 + 0] + h2*Wu2[j2*2 + 0];
  float p1 = h1*Wu2[j1*2 + 1] + h2*Wu2[j2*2 + 1];
  #pragma unroll
  for (int o = 32; o; o >>= 1) { p0 += __shfl_xor(p0, o); p1 += __shfl_xor(p1, o); }
  if (lane == 0) {
    const float hh0 = ue0 + p0 + bu2[0];
    const float hh1 = ue1 + p1 + bu2[1];
    const float mu = 0.5f*(hh0 + hh1);
    const float dd = hh0 - mu;
    const float inv = rsqrtf(dd*dd + 1e-5f);
    float* gout = ws + UE_OFF;
    gout[u*2 + 0] =  dd*inv*lng[0] + lnb[0];
    gout[u*2 + 1] = -dd*inv*lng[1] + lnb[1];
  }
}

// head: 2 ->128 ->128 ->2 + sigmoid. 32 rows / 256-thread block, 8 rows/wave.
__global__ __launch_bounds__(256) void head_kernel(
    const float* __restrict__ g,
    const float* __restrict__ Wf1, const float* __restrict__ bf1,
    const float* __restrict__ Wf2, const float* __restrict__ bf2,
    const float* __restrict__ Wf3, const float* __restrict__ bf3,
    float* __restrict__ out) {
  __shared__ float a_s[32][129];
  const int tid = threadIdx.x;
  const int rl = tid >> 3, sub = tid & 7;
  const int r = blockIdx.x*32 + rl;
  const float g0 = g[r*2 + 0], g1 = g[r*2 + 1];
  #pragma unroll
  for (int jj = 0; jj < 16; ++jj) {
    const int j = sub*16 + jj;
    a_s[rl][j] = LEAKY(fmaf(g0, Wf1[j], fmaf(g1, Wf1[128 + j], bf1[j])));
  }
  __syncthreads();
  float h2[16];
  #pragma unroll
  for (int jj = 0; jj < 16; ++jj) h2[jj] = bf2[sub*16 + jj];
  for (int k = 0; k < 128; ++k) {
    const float ak = a_s[rl][k];
    const float4* wrow = (const float4*)(Wf2 + k*128 + sub*16);
    const float4 w0 = wrow[0], w1 = wrow[1], w2 = wrow[2], w3 = wrow[3];
    h2[0]  = fmaf(ak, w0.x, h2[0]);  h2[1]  = fmaf(ak, w0.y, h2[1]);
    h2[2]  = fmaf(ak, w0.z, h2[2]);  h2[3]  = fmaf(ak, w0.w, h2[3]);
    h2[4]  = fmaf(ak, w1.x, h2[4]);  h2[5]  = fmaf(ak, w1.y, h2[5]);
    h2[6]  = fmaf(ak, w1.z, h2[6]);  h2[7]  = fmaf(ak, w1.w, h2[7]);
    h2[8]  = fmaf(ak, w2.x, h2[8]);  h2[9]  = fmaf(ak, w2.y, h2[9]);
    h2[10] = fmaf(ak, w2.z, h2[10]); h2[11] = fmaf(ak, w2.w, h2[11]);
    h2[12] = fmaf(ak, w3.x, h2[12]); h2[13] = fmaf(ak, w3.y, h2[13]);
    h2[14] = fmaf(ak, w3.z, h2[14]); h2[15] = fmaf(ak, w3.w, h2[15]);
  }
  float p0 = 0.f, p1 = 0.f;
  #pragma unroll
  for (int jj = 0; jj < 16; ++jj) {
    const float hv = LEAKY(h2[jj]);
    const int j = sub*16 + jj;
    p0 = fmaf(hv, Wf3[j*2 + 0], p0);
    p1 = fmaf(hv, Wf3[j*2 + 1], p1);
  }
  #pragma unroll
  for (int o = 4; o; o >>= 1) { p0 += __shfl_xor(p0, o); p1 += __shfl_xor(p1, o); }
  if (sub == 0) {
    out[r*2 + 0] = 1.f/(1.f + expf(-(p0 + bf3[0])));
    out[r*2 + 1] = 1.f/(1.f + expf(-(p1 + bf3[1])));
  }
}

extern "C" void kernel_launch(void* const* d_in, const int* in_sizes, int n_in,
                              void* d_out, int out_size, void* d_ws, size_t ws_size,
                              hipStream_t stream) {
  (void)in_sizes; (void)n_in; (void)out_size; (void)ws_size;
  const float* x_ue      = (const float*)d_in[0];
  const float* x_ap      = (const float*)d_in[1];
  const float* edge_attr = (const float*)d_in[2];
  const int*   edge_src  = (const int*)d_in[3];
  const float* Wn1u = (const float*)d_in[5];
  const float* bn1u = (const float*)d_in[6];
  const float* Wn2u = (const float*)d_in[7];
  const float* bn2u = (const float*)d_in[8];
  const float* Wn1a = (const float*)d_in[9];
  const float* bn1a = (const float*)d_in[10];
  const float* Wn2a = (const float*)d_in[11];
  const float* bn2a = (const float*)d_in[12];
  const float* We1  = (const float*)d_in[13];
  const float* be1  = (const float*)d_in[14];
  const float* We2  = (const float*)d_in[15];
  const float* be2  = (const float*)d_in[16];
  const float* strong = (const float*)d_in[17];
  const float* inits  = (const float*)d_in[18];
  const float* update = (const float*)d_in[19];
  const float* Wu1  = (const float*)d_in[20];
  const float* bu1  = (const float*)d_in[21];
  const float* Wu2  = (const float*)d_in[22];
  const float* bu2  = (const float*)d_in[23];
  const float* ln_g = (const float*)d_in[24];
  const float* ln_b = (const float*)d_in[25];
  const float* Wf1  = (const float*)d_in[26];
  const float* bf1  = (const float*)d_in[27];
  const float* Wf2  = (const float*)d_in[28];
  const float* bf2  = (const float*)d_in[29];
  const float* Wf3  = (const float*)d_in[30];
  const float* bf3  = (const float*)d_in[31];

  float* ws = (float*)d_ws;

  prep_kernel<<<1089, 256, 0, stream>>>(x_ue, x_ap, edge_attr,
                                        Wn1u, bn1u, Wn2u, bn2u,
                                        Wn1a, bn1a, Wn2a, bn2a,
                                        We1, be1, We2, be2,
                                        strong, inits, update, ws);
  circuit_kernel<<<4096, 128, 0, stream>>>(ws, edge_src,
                                           Wu1, bu1, Wu2, bu2, ln_g, ln_b);
  head_kernel<<<256, 256, 0, stream>>>(ws + UE_OFF, Wf1, bf1, Wf2, bf2, Wf3, bf3,
                                       (float*)d_out);
}

// Round 4
// 65.126 us; speedup vs baseline: 1.0333x; 1.0333x over previous
//
#include <hip/hip_runtime.h>

#define LEAKY(x) ((x) > 0.0f ? (x) : 0.01f * (x))

// ws float layout
#define UE_OFF 0                 // 16384 floats (reused as g-output after circuit)
#define AP_OFF 16384             // 4096
#define EA_OFF 20480             // 49152
#define ME_OFF 69632             // 32   : M_edge 4x4 complex
#define U0C_OFF 69664            // 128  : U0 cols {0,4,8,12}, [j][r] col-major
#define U1T_OFF 69792            // 512  : U1 [q][r] (col-major)
#define GP_OFF 70304             // 1536 : 3 x permuted G_w [(c*2+n)*16 + (c'*2+n')]

__device__ __forceinline__ float2 cmul(float2 a, float2 b) {
  return make_float2(fmaf(a.x, b.x, -a.y * b.y), fmaf(a.x, b.y, a.y * b.x));
}
__device__ __forceinline__ float2 cmulc(float2 a, float2 b) {  // conj(a)*b
  return make_float2(fmaf(a.x, b.x, a.y * b.y), fmaf(a.x, b.y, -a.y * b.x));
}
__device__ __forceinline__ float2 cadd(float2 a, float2 b) {
  return make_float2(a.x + b.x, a.y + b.y);
}
__device__ __forceinline__ float2 csub(float2 a, float2 b) {
  return make_float2(a.x - b.x, a.y - b.y);
}
__device__ __forceinline__ void swap2(float2& a, float2& b) {
  float2 t = a; a = b; b = t;
}

struct C2 { float2 e[4]; }; // row-major 2x2 complex

__device__ C2 cmm(const C2& A, const C2& B) {
  C2 R;
  #pragma unroll
  for (int r = 0; r < 2; ++r)
    #pragma unroll
    for (int c = 0; c < 2; ++c)
      R.e[r*2+c] = cadd(cmul(A.e[r*2+0], B.e[0*2+c]), cmul(A.e[r*2+1], B.e[1*2+c]));
  return R;
}
__device__ C2 gRX(float t) {
  float s = __sinf(0.5f*t), c = __cosf(0.5f*t);
  C2 M;
  M.e[0] = make_float2(c, 0.f);  M.e[1] = make_float2(0.f, -s);
  M.e[2] = make_float2(0.f, -s); M.e[3] = make_float2(c, 0.f);
  return M;
}
__device__ C2 gRY(float t) {
  float s = __sinf(0.5f*t), c = __cosf(0.5f*t);
  C2 M;
  M.e[0] = make_float2(c, 0.f);  M.e[1] = make_float2(-s, 0.f);
  M.e[2] = make_float2(s, 0.f);  M.e[3] = make_float2(c, 0.f);
  return M;
}
__device__ C2 gRZ(float t) {
  float s = __sinf(0.5f*t), c = __cosf(0.5f*t);
  C2 M;
  M.e[0] = make_float2(c, -s);    M.e[1] = make_float2(0.f, 0.f);
  M.e[2] = make_float2(0.f, 0.f); M.e[3] = make_float2(c, s);
  return M;
}
__device__ C2 gROT(float phi, float th, float om) {
  return cmm(cmm(gRZ(om), gRY(th)), gRZ(phi));
}

// 2-layer MLP encoder, 8 threads per row, 32 rows per 256-thread block.
template<int D>
__device__ void enc_rows(const float* __restrict__ x, int rbase,
                         const float* __restrict__ W1, const float* __restrict__ b1,
                         const float* __restrict__ W2, const float* __restrict__ b2,
                         float* __restrict__ out) {
  const int tid = threadIdx.x;
  const int r = rbase + (tid >> 3), sub = tid & 7;
  float xi[D];
  #pragma unroll
  for (int k = 0; k < D; ++k) xi[k] = x[r*D + k];
  float o0 = 0.f, o1 = 0.f;
  #pragma unroll
  for (int jj = 0; jj < 16; ++jj) {
    int j = jj*8 + sub;
    float h = b1[j];
    #pragma unroll
    for (int k = 0; k < D; ++k) h = fmaf(xi[k], W1[k*128 + j], h);
    h = LEAKY(h);
    o0 = fmaf(h, W2[j*2 + 0], o0);
    o1 = fmaf(h, W2[j*2 + 1], o1);
  }
  #pragma unroll
  for (int o = 4; o; o >>= 1) { o0 += __shfl_xor(o0, o); o1 += __shfl_xor(o1, o); }
  if (sub == 0) {
    out[r*2 + 0] = o0 + b2[0];
    out[r*2 + 1] = o1 + b2[1];
  }
}

// Fused: 3 encoders + gate-algebra precompute (block 1088).
__global__ __launch_bounds__(256) void prep_kernel(
    const float* __restrict__ x_ue, const float* __restrict__ x_ap,
    const float* __restrict__ edge_attr,
    const float* __restrict__ Wn1u, const float* __restrict__ bn1u,
    const float* __restrict__ Wn2u, const float* __restrict__ bn2u,
    const float* __restrict__ Wn1a, const float* __restrict__ bn1a,
    const float* __restrict__ Wn2a, const float* __restrict__ bn2a,
    const float* __restrict__ We1,  const float* __restrict__ be1,
    const float* __restrict__ We2,  const float* __restrict__ be2,
    const float* __restrict__ strongp, const float* __restrict__ initsp,
    const float* __restrict__ updatep, float* __restrict__ ws) {
  const int bi = blockIdx.x;
  if (bi < 256) {
    enc_rows<8>(x_ue, bi*32, Wn1u, bn1u, Wn2u, bn2u, ws + UE_OFF);
  } else if (bi < 320) {
    enc_rows<8>(x_ap, (bi-256)*32, Wn1a, bn1a, Wn2a, bn2a, ws + AP_OFF);
  } else if (bi < 1088) {
    enc_rows<4>(edge_attr, (bi-320)*32, We1, be1, We2, be2, ws + EA_OFF);
  } else {
    // ---- gate algebra block ----
    __shared__ float2 U2s[16][17];
    const int tid = threadIdx.x;
    if (tid < 48) {
      // build U_k (k = tid>>4) column col = tid&15.
      // q-space bit masks: wire3=8, nb=4, wire7=2, wire8=1.
      const int k = tid >> 4, col = tid & 15;
      float2 u[16];
      #pragma unroll
      for (int r = 0; r < 16; ++r) u[r] = make_float2(r == col ? 1.f : 0.f, 0.f);
      #pragma unroll
      for (int l = 0; l < 2; ++l) {
        #pragma unroll
        for (int j = 0; j < 4; ++j) {
          const float* p = updatep + k*24 + l*12 + j*3;
          C2 U = gROT(p[0], p[1], p[2]);
          const int m = 8 >> j;
          #pragma unroll
          for (int r = 0; r < 16; ++r)
            if (!(r & m)) {
              float2 t0 = u[r], t1 = u[r | m];
              u[r]     = cadd(cmul(U.e[0], t0), cmul(U.e[1], t1));
              u[r | m] = cadd(cmul(U.e[2], t0), cmul(U.e[3], t1));
            }
        }
        // CX list: l=0: (8->4),(4->2),(2->1),(1->8); l=1: (8->2),(4->1),(2->8),(1->4)
        #pragma unroll
        for (int j = 0; j < 4; ++j) {
          const int mc = 8 >> j;
          const int mt0[4] = {4, 2, 1, 8};
          const int mt1[4] = {2, 1, 8, 4};
          const int mt = (l == 0) ? mt0[j] : mt1[j];
          #pragma unroll
          for (int r = 0; r < 16; ++r)
            if ((r & mc) && !(r & mt)) swap2(u[r], u[r | mt]);
        }
      }
      if (k == 0) {
        if (!(col & 3)) {
          const int jc = col >> 2;
          #pragma unroll
          for (int r = 0; r < 16; ++r) {
            ws[U0C_OFF + (jc*16 + r)*2 + 0] = u[r].x;
            ws[U0C_OFF + (jc*16 + r)*2 + 1] = u[r].y;
          }
        }
      } else if (k == 1) {
        #pragma unroll
        for (int r = 0; r < 16; ++r) {
          ws[U1T_OFF + (col*16 + r)*2 + 0] = u[r].x;
          ws[U1T_OFF + (col*16 + r)*2 + 1] = u[r].y;
        }
      } else {
        #pragma unroll
        for (int r = 0; r < 16; ++r) U2s[col][r] = u[r];   // U2s[q][t] = U2[t][q]
      }
    }
    if (tid == 48) {
      // ---- M_edge 4x4 (basis (b_e<<1)|b_nb)
      float2 M[4][4];
      #pragma unroll
      for (int r = 0; r < 4; ++r)
        #pragma unroll
        for (int c = 0; c < 4; ++c)
          M[r][c] = make_float2(r == c ? 1.f : 0.f, 0.f);
      auto rowpair = [&](int r0, int r1, C2 U) {
        #pragma unroll
        for (int c = 0; c < 4; ++c) {
          float2 a0 = M[r0][c], a1 = M[r1][c];
          M[r0][c] = cadd(cmul(U.e[0], a0), cmul(U.e[1], a1));
          M[r1][c] = cadd(cmul(U.e[2], a0), cmul(U.e[3], a1));
        }
      };
      auto rowswap = [&](int r0, int r1) {
        #pragma unroll
        for (int c = 0; c < 4; ++c) swap2(M[r0][c], M[r1][c]);
      };
      rowpair(1, 3, gRX(initsp[0]));
      rowpair(2, 3, gRY(initsp[1]));
      #pragma unroll
      for (int l = 0; l < 2; ++l) {
        C2 Re = gROT(strongp[l*6+0], strongp[l*6+1], strongp[l*6+2]);
        C2 Rn = gROT(strongp[l*6+3], strongp[l*6+4], strongp[l*6+5]);
        rowpair(0, 2, Re); rowpair(1, 3, Re);
        rowpair(0, 1, Rn); rowpair(2, 3, Rn);
        rowswap(2, 3);
        rowswap(1, 3);
      }
      #pragma unroll
      for (int r = 0; r < 4; ++r)
        #pragma unroll
        for (int c = 0; c < 4; ++c) {
          ws[ME_OFF + (r*4 + c)*2 + 0] = M[r][c].x;
          ws[ME_OFF + (r*4 + c)*2 + 1] = M[r][c].y;
        }
    }
    __syncthreads();
    if (tid < 64) {
      // G_w[q,q'] = sum_t conj(U2[t,q]) s_w(t) U2[t,q'], stored permuted:
      // GP[w][(c*2+n)*16 + (c'*2+n')] with q=m(c,n)=((c&4)<<1)|(n<<2)|(c&3)
      const int c = tid >> 3, cp = tid & 7;
      #pragma unroll
      for (int n = 0; n < 2; ++n)
        #pragma unroll
        for (int np = 0; np < 2; ++np) {
          const int q  = ((c  & 4) << 1) | (n  << 2) | (c  & 3);
          const int qp = ((cp & 4) << 1) | (np << 2) | (cp & 3);
          float2 g3 = make_float2(0,0), g7 = g3, g8 = g3;
          #pragma unroll
          for (int t = 0; t < 16; ++t) {
            float2 pr = cmulc(U2s[q][t], U2s[qp][t]);
            g3 = (t & 8) ? csub(g3, pr) : cadd(g3, pr);
            g7 = (t & 2) ? csub(g7, pr) : cadd(g7, pr);
            g8 = (t & 1) ? csub(g8, pr) : cadd(g8, pr);
          }
          const int idx = (c*2 + n)*16 + (cp*2 + np);
          ws[GP_OFF + (0*256 + idx)*2 + 0] = g3.x;
          ws[GP_OFF + (0*256 + idx)*2 + 1] = g3.y;
          ws[GP_OFF + (1*256 + idx)*2 + 0] = g7.x;
          ws[GP_OFF + (1*256 + idx)*2 + 1] = g7.y;
          ws[GP_OFF + (2*256 + idx)*2 + 0] = g8.x;
          ws[GP_OFF + (2*256 + idx)*2 + 1] = g8.y;
        }
    }
  }
}

// One wave per UE; branch-traced simulation. Writes g (2 floats/UE) into UE region.
__global__ __launch_bounds__(128) void circuit_kernel(
    float* __restrict__ ws, const int* __restrict__ esrc,
    const float* __restrict__ Wu1, const float* __restrict__ bu1,
    const float* __restrict__ Wu2, const float* __restrict__ bu2,
    const float* __restrict__ lng, const float* __restrict__ lnb) {
  __shared__ float2 consts[1104];  // ME(16) | U0c(64) | U1t(256) | GP(768) — contiguous in ws
  __shared__ float2 pr_s[2][3][4];
  __shared__ float2 psi0[2][2][16];
  __shared__ float2 psi2[2][8][16];
  const int tid = threadIdx.x, wv = tid >> 6, lane = tid & 63;
  const int u = blockIdx.x*2 + wv;

  // --- A: stage constants (ME..GP are contiguous 1104 float2 in ws)
  {
    const float2* src = (const float2*)(ws + ME_OFF);
    #pragma unroll
    for (int i = 0; i < 9; ++i) {
      const int idx = i*128 + tid;
      if (idx < 1104) consts[idx] = src[idx];
    }
  }
  const float2* MEs = consts;
  const float2* U0c = consts + 16;    // [j][r] : j*16+r
  const float2* U1t = consts + 80;    // [q][r] : q*16+r
  const float2* GPs = consts + 336;   // [w][idx]

  // --- B: init single-qubit states + pair vectors
  const float* uep = ws + UE_OFF;
  const float* app = ws + AP_OFF;
  const float* eap = ws + EA_OFF;
  const float ue0 = uep[u*2 + 0], ue1 = uep[u*2 + 1];
  auto mkv = [](float aa, float bb, float2& v0, float2& v1) {
    const float sa = __sinf(0.5f*aa), ca = __cosf(0.5f*aa);
    const float sb = __sinf(0.5f*bb), cb = __cosf(0.5f*bb);
    v0 = make_float2(cb*ca, -sb*ca);
    v1 = make_float2(sa*sb, -sa*cb);
  };
  float2 t0, t1;
  mkv(ue0, ue1, t0, t1);
  if (lane < 12) {
    const int i = lane >> 2, r = lane & 3;
    float2 ev0, ev1, nv0, nv1;
    mkv(eap[(u*3 + i)*2 + 0], eap[(u*3 + i)*2 + 1], ev0, ev1);
    const int s = esrc[u*3 + i];
    mkv(app[s*2 + 0], app[s*2 + 1], nv0, nv1);
    float2 in4[4] = {cmul(ev0, nv0), cmul(ev0, nv1), cmul(ev1, nv0), cmul(ev1, nv1)};
    float2 acc = make_float2(0.f, 0.f);
    #pragma unroll
    for (int c = 0; c < 4; ++c) acc = cadd(acc, cmul(MEs[r*4 + c], in4[c]));
    pr_s[wv][i][r] = acc;
  }
  __syncthreads();

  // --- C: block0 — 2 branches x 16 rows (lanes 0..31)
  if (lane < 32) {
    const int b = lane >> 4, row = lane & 15;
    float2 acc = make_float2(0.f, 0.f);
    #pragma unroll
    for (int j = 0; j < 4; ++j) {            // j = (c3<<1)|n -> col q'=4j
      float2 phi = pr_s[wv][0][(b << 1) | (j & 1)];
      float2 coef = cmul((j >> 1) ? t1 : t0, phi);
      acc = cadd(acc, cmul(U0c[j*16 + row], coef));
    }
    psi0[wv][b][row] = acc;
  }
  __syncthreads();

  // --- D: block1 — 8 input-branches x 16 rows, 2 rows/lane
  {
    const int ibr = lane >> 3, rp = lane & 7;
    const int db = ibr >> 2, da = (ibr >> 1) & 1, dbp = ibr & 1;
    const float2 f10 = pr_s[wv][1][(dbp << 1) | 0];
    const float2 f11 = pr_s[wv][1][(dbp << 1) | 1];
    float2 chi[8];
    #pragma unroll
    for (int cc = 0; cc < 8; ++cc)
      chi[cc] = psi0[wv][db][((cc & 4) << 1) | (da << 2) | (cc & 3)];
    float2 o0 = make_float2(0.f, 0.f), o1 = o0;
    #pragma unroll
    for (int q = 0; q < 16; ++q) {
      const int cc = ((q >> 3) << 2) | (q & 3);
      float2 xq = cmul(chi[cc], (q & 4) ? f11 : f10);
      o0 = cadd(o0, cmul(U1t[q*16 + rp],     xq));
      o1 = cadd(o1, cmul(U1t[q*16 + rp + 8], xq));
    }
    psi2[wv][ibr][rp]     = o0;
    psi2[wv][ibr][rp + 8] = o1;
  }
  __syncthreads();

  // --- E: branch Gram matrix R[c,c'] (one entry per lane)
  const int c = lane >> 3, cp = lane & 7;
  float2 R = make_float2(0.f, 0.f);
  #pragma unroll
  for (int br = 0; br < 8; ++br)
    #pragma unroll
    for (int a2 = 0; a2 < 2; ++a2) {
      float2 z1 = psi2[wv][br][((c  & 4) << 1) | (a2 << 2) | (c  & 3)];
      float2 z2 = psi2[wv][br][((cp & 4) << 1) | (a2 << 2) | (cp & 3)];
      R.x += z1.x*z2.x + z1.y*z2.y;          // z1 * conj(z2)
      R.y += z1.y*z2.x - z1.x*z2.y;
    }

  // --- F: rho2, K_w, E_w
  const float2 f20 = pr_s[wv][2][0], f21 = pr_s[wv][2][1];
  const float2 f22 = pr_s[wv][2][2], f23 = pr_s[wv][2][3];
  float2 rho[2][2];
  rho[0][0] = make_float2(f20.x*f20.x + f20.y*f20.y + f22.x*f22.x + f22.y*f22.y, 0.f);
  rho[1][1] = make_float2(f21.x*f21.x + f21.y*f21.y + f23.x*f23.x + f23.y*f23.y, 0.f);
  rho[0][1] = make_float2(fmaf(f20.x,f21.x,f20.y*f21.y) + fmaf(f22.x,f23.x,f22.y*f23.y),
                          (f20.y*f21.x - f20.x*f21.y) + (f22.y*f23.x - f22.x*f23.y));
  rho[1][0] = make_float2(rho[0][1].x, -rho[0][1].y);

  float ev[3];
  #pragma unroll
  for (int w = 0; w < 3; ++w) {
    float2 K = make_float2(0.f, 0.f);
    #pragma unroll
    for (int n = 0; n < 2; ++n)
      #pragma unroll
      for (int np = 0; np < 2; ++np) {
        float2 g = GPs[w*256 + (c*2 + n)*16 + (cp*2 + np)];
        K = cadd(K, cmul(g, rho[np][n]));
      }
    ev[w] = K.x*R.x + K.y*R.y;               // Re(K * conj(R))
  }
  #pragma unroll
  for (int o = 32; o; o >>= 1) {
    ev[0] += __shfl_xor(ev[0], o);
    ev[1] += __shfl_xor(ev[1], o);
    ev[2] += __shfl_xor(ev[2], o);
  }

  // --- G: Wu MLP + residual + LN -> g
  const int j1 = lane, j2 = lane + 64;
  float in5[5] = {ue0, ue1, ev[0], ev[1], ev[2]};
  float h1 = bu1[j1], h2 = bu1[j2];
  #pragma unroll
  for (int k = 0; k < 5; ++k) {
    h1 = fmaf(in5[k], Wu1[k*128 + j1], h1);
    h2 = fmaf(in5[k], Wu1[k*128 + j2], h2);
  }
  h1 = LEAKY(h1); h2 = LEAKY(h2);
  float p0 = h1*Wu2[j1*2 + 0] + h2*Wu2[j2*2 + 0];
  float p1 = h1*Wu2[j1*2 + 1] + h2*Wu2[j2*2 + 1];
  #pragma unroll
  for (int o = 32; o; o >>= 1) { p0 += __shfl_xor(p0, o); p1 += __shfl_xor(p1, o); }
  if (lane == 0) {
    const float hh0 = ue0 + p0 + bu2[0];
    const float hh1 = ue1 + p1 + bu2[1];
    const float mu = 0.5f*(hh0 + hh1);
    const float dd = hh0 - mu;
    const float inv = rsqrtf(dd*dd + 1e-5f);
    float* gout = ws + UE_OFF;
    gout[u*2 + 0] =  dd*inv*lng[0] + lnb[0];
    gout[u*2 + 1] = -dd*inv*lng[1] + lnb[1];
  }
}

// head: 2 ->128 ->128 ->2 + sigmoid. 32 rows / 256-thread block, 8 rows/wave.
__global__ __launch_bounds__(256) void head_kernel(
    const float* __restrict__ g,
    const float* __restrict__ Wf1, const float* __restrict__ bf1,
    const float* __restrict__ Wf2, const float* __restrict__ bf2,
    const float* __restrict__ Wf3, const float* __restrict__ bf3,
    float* __restrict__ out) {
  __shared__ float a_s[32][129];
  const int tid = threadIdx.x;
  const int rl = tid >> 3, sub = tid & 7;
  const int r = blockIdx.x*32 + rl;
  const float g0 = g[r*2 + 0], g1 = g[r*2 + 1];
  #pragma unroll
  for (int jj = 0; jj < 16; ++jj) {
    const int j = sub*16 + jj;
    a_s[rl][j] = LEAKY(fmaf(g0, Wf1[j], fmaf(g1, Wf1[128 + j], bf1[j])));
  }
  __syncthreads();
  float h2[16];
  #pragma unroll
  for (int jj = 0; jj < 16; ++jj) h2[jj] = bf2[sub*16 + jj];
  for (int k = 0; k < 128; ++k) {
    const float ak = a_s[rl][k];
    const float4* wrow = (const float4*)(Wf2 + k*128 + sub*16);
    const float4 w0 = wrow[0], w1 = wrow[1], w2 = wrow[2], w3 = wrow[3];
    h2[0]  = fmaf(ak, w0.x, h2[0]);  h2[1]  = fmaf(ak, w0.y, h2[1]);
    h2[2]  = fmaf(ak, w0.z, h2[2]);  h2[3]  = fmaf(ak, w0.w, h2[3]);
    h2[4]  = fmaf(ak, w1.x, h2[4]);  h2[5]  = fmaf(ak, w1.y, h2[5]);
    h2[6]  = fmaf(ak, w1.z, h2[6]);  h2[7]  = fmaf(ak, w1.w, h2[7]);
    h2[8]  = fmaf(ak, w2.x, h2[8]);  h2[9]  = fmaf(ak, w2.y, h2[9]);
    h2[10] = fmaf(ak, w2.z, h2[10]); h2[11] = fmaf(ak, w2.w, h2[11]);
    h2[12] = fmaf(ak, w3.x, h2[12]); h2[13] = fmaf(ak, w3.y, h2[13]);
    h2[14] = fmaf(ak, w3.z, h2[14]); h2[15] = fmaf(ak, w3.w, h2[15]);
  }
  float p0 = 0.f, p1 = 0.f;
  #pragma unroll
  for (int jj = 0; jj < 16; ++jj) {
    const float hv = LEAKY(h2[jj]);
    const int j = sub*16 + jj;
    p0 = fmaf(hv, Wf3[j*2 + 0], p0);
    p1 = fmaf(hv, Wf3[j*2 + 1], p1);
  }
  #pragma unroll
  for (int o = 4; o; o >>= 1) { p0 += __shfl_xor(p0, o); p1 += __shfl_xor(p1, o); }
  if (sub == 0) {
    out[r*2 + 0] = 1.f/(1.f + expf(-(p0 + bf3[0])));
    out[r*2 + 1] = 1.f/(1.f + expf(-(p1 + bf3[1])));
  }
}

extern "C" void kernel_launch(void* const* d_in, const int* in_sizes, int n_in,
                              void* d_out, int out_size, void* d_ws, size_t ws_size,
                              hipStream_t stream) {
  (void)in_sizes; (void)n_in; (void)out_size; (void)ws_size;
  const float* x_ue      = (const float*)d_in[0];
  const float* x_ap      = (const float*)d_in[1];
  const float* edge_attr = (const float*)d_in[2];
  const int*   edge_src  = (const int*)d_in[3];
  const float* Wn1u = (const float*)d_in[5];
  const float* bn1u = (const float*)d_in[6];
  const float* Wn2u = (const float*)d_in[7];
  const float* bn2u = (const float*)d_in[8];
  const float* Wn1a = (const float*)d_in[9];
  const float* bn1a = (const float*)d_in[10];
  const float* Wn2a = (const float*)d_in[11];
  const float* bn2a = (const float*)d_in[12];
  const float* We1  = (const float*)d_in[13];
  const float* be1  = (const float*)d_in[14];
  const float* We2  = (const float*)d_in[15];
  const float* be2  = (const float*)d_in[16];
  const float* strong = (const float*)d_in[17];
  const float* inits  = (const float*)d_in[18];
  const float* update = (const float*)d_in[19];
  const float* Wu1  = (const float*)d_in[20];
  const float* bu1  = (const float*)d_in[21];
  const float* Wu2  = (const float*)d_in[22];
  const float* bu2  = (const float*)d_in[23];
  const float* ln_g = (const float*)d_in[24];
  const float* ln_b = (const float*)d_in[25];
  const float* Wf1  = (const float*)d_in[26];
  const float* bf1  = (const float*)d_in[27];
  const float* Wf2  = (const float*)d_in[28];
  const float* bf2  = (const float*)d_in[29];
  const float* Wf3  = (const float*)d_in[30];
  const float* bf3  = (const float*)d_in[31];

  float* ws = (float*)d_ws;

  prep_kernel<<<1089, 256, 0, stream>>>(x_ue, x_ap, edge_attr,
                                        Wn1u, bn1u, Wn2u, bn2u,
                                        Wn1a, bn1a, Wn2a, bn2a,
                                        We1, be1, We2, be2,
                                        strong, inits, update, ws);
  circuit_kernel<<<4096, 128, 0, stream>>>(ws, edge_src,
                                           Wu1, bu1, Wu2, bu2, ln_g, ln_b);
  head_kernel<<<256, 256, 0, stream>>>(ws + UE_OFF, Wf1, bf1, Wf2, bf2, Wf3, bf3,
                                       (float*)d_out);
}